// Round 6
// baseline (273.220 us; speedup 1.0000x reference)
//
#include <hip/hip_runtime.h>

typedef unsigned short u16;
typedef unsigned int u32;
typedef __bf16 bf16x8 __attribute__((ext_vector_type(8)));
typedef float f32x4 __attribute__((ext_vector_type(4)));

#define BDIM 4
#define TDIM 2048
#define EDIM 1024
#define HDIM 16
#define HS 64
#define MROWS (BDIM * TDIM)
#define FFNP 128   // FFN_HID=100 padded to 128
#define QSTR 3072  // fused qkv row stride

__device__ __forceinline__ u16 f2bf(float f) {
    __bf16 h = (__bf16)f;
    return __builtin_bit_cast(u16, h);
}

__device__ __forceinline__ void glds16(const void* g, void* l) {
    __builtin_amdgcn_global_load_lds(
        (__attribute__((address_space(1))) const void*)g,
        (__attribute__((address_space(3))) void*)l, 16, 0, 0);
}

// ---------------- weight transpose + f32->bf16 (+zero padding) ----------------
__global__ __launch_bounds__(256) void transpose_pad(
    const float* __restrict__ src, u16* __restrict__ dst,
    int K, int N, int Kpad, int Npad)
{
    __shared__ u16 sm[64][72];
    int k0 = blockIdx.x * 64, n0 = blockIdx.y * 64;
    int tid = threadIdx.x;
#pragma unroll
    for (int i = 0; i < 16; i++) {
        int idx = i * 256 + tid;
        int kl = idx >> 6, nl = idx & 63;
        int k = k0 + kl, n = n0 + nl;
        float v = (k < K && n < N) ? src[(size_t)k * N + n] : 0.f;
        sm[kl][nl] = f2bf(v);
    }
    __syncthreads();
#pragma unroll
    for (int i = 0; i < 16; i++) {
        int idx = i * 256 + tid;
        int nl = idx >> 6, kl = idx & 63;
        int n = n0 + nl, k = k0 + kl;
        if (n < Npad && k < Kpad) dst[(size_t)n * Kpad + k] = sm[kl][nl];
    }
}

// ---------------- V transpose per head: qkv[B,T,3072] -> [(B*H)*HS][T] --------
__global__ __launch_bounds__(256) void vtrans(
    const u16* __restrict__ qkv, u16* __restrict__ vt)
{
    __shared__ u16 sm[64][65];
    int t0 = blockIdx.x * 64, h = blockIdx.y, b = blockIdx.z;
    int tid = threadIdx.x;
    int r = tid >> 3, c8 = (tid & 7) * 8;
#pragma unroll
    for (int rr = 0; rr < 2; rr++) {
        int row = r + rr * 32;
        union { uint4 v; u16 us[8]; } u;
        u.v = *(const uint4*)&qkv[((size_t)b * TDIM + t0 + row) * QSTR + 2048 + h * HS + c8];
#pragma unroll
        for (int e = 0; e < 8; e++) sm[row][c8 + e] = u.us[e];
    }
    __syncthreads();
#pragma unroll
    for (int rr = 0; rr < 2; rr++) {
        int d = r + rr * 32;
        union { uint4 v; u16 us[8]; } u;
#pragma unroll
        for (int e = 0; e < 8; e++) u.us[e] = sm[c8 + e][d];
        *(uint4*)&vt[((size_t)(b * HDIM + h) * HS + d) * TDIM + t0 + c8] = u.v;
    }
}

// ---------------- LayerNorm rows (one wave per row), f32 in -> bf16 out -------
__global__ __launch_bounds__(256) void ln_rows(
    const float* __restrict__ X, const float* __restrict__ G,
    const float* __restrict__ Bv, u16* __restrict__ H)
{
    int w = threadIdx.x >> 6, l = threadIdx.x & 63;
    int row = blockIdx.x * 4 + w;
    const float* xr = X + (size_t)row * EDIM;
    float4 v[4];
    float s = 0.f, s2 = 0.f;
#pragma unroll
    for (int i = 0; i < 4; i++) {
        v[i] = *(const float4*)&xr[l * 4 + i * 256];
        s += v[i].x + v[i].y + v[i].z + v[i].w;
        s2 += v[i].x * v[i].x + v[i].y * v[i].y + v[i].z * v[i].z + v[i].w * v[i].w;
    }
#pragma unroll
    for (int off = 1; off < 64; off <<= 1) {
        s += __shfl_xor(s, off, 64);
        s2 += __shfl_xor(s2, off, 64);
    }
    float mean = s * (1.f / EDIM);
    float var = s2 * (1.f / EDIM) - mean * mean;
    float rstd = rsqrtf(var + 1e-5f);
#pragma unroll
    for (int i = 0; i < 4; i++) {
        int c = l * 4 + i * 256;
        float4 gg = *(const float4*)&G[c];
        float4 bb = *(const float4*)&Bv[c];
        u16 o0 = f2bf((v[i].x - mean) * rstd * gg.x + bb.x);
        u16 o1 = f2bf((v[i].y - mean) * rstd * gg.y + bb.y);
        u16 o2 = f2bf((v[i].z - mean) * rstd * gg.z + bb.z);
        u16 o3 = f2bf((v[i].w - mean) * rstd * gg.w + bb.w);
        uint2 pk;
        pk.x = (u32)o0 | ((u32)o1 << 16);
        pk.y = (u32)o2 | ((u32)o3 << 16);
        *(uint2*)&H[(size_t)row * EDIM + c] = pk;
    }
}

// ======= 256x256 8-phase GEMM (T2+T3+T4+T5), Bt input ([N][ldb]) ==============
// MODE 0: C = A*B -> bf16 Cb.  MODE 1: C = resid + A*B + bias -> f32 Cf.
// LDS: [dbuf][A/B][half][128 rows x 64 cols] bf16, XOR-swizzled (chunk ^= row&7)
// via linear global_load_lds dest + pre-swizzled global source.
// Stage map (iter j, t=2j): ph1:A0(t+1) ph2:A1(t+1) ph3:B1(t+1) ph4:B1(t+2)
// ph5:A0(t+2) ph6:A1(t+2) ph7:B0(t+2) ph8:B0(t+3); B0(t+1) staged prev ph8.
// WAR: A-halves read ph1,2,4 (restaged ph5/6); B-halves read ph1,3 (ph4/7) --
// every overwrite issue is >=1 barrier after that region's last ds_read.
// RAW: vmcnt(2) at ph4/ph8 + barrier => next K-tile fully landed.
#define LDA4(d, mfb)                                                          \
    _Pragma("unroll") for (int mi = 0; mi < 4; mi++)                          \
    _Pragma("unroll") for (int ks = 0; ks < 2; ks++)                          \
        a[mi][ks] = *(const bf16x8*)&L[d][0][wm][((mfb + mi) * 16 + lr) * 64  \
                        + (((lg + 4 * ks) ^ (lr & 7)) << 3)];
#define LDB2(d, nfb)                                                          \
    _Pragma("unroll") for (int ni = 0; ni < 2; ni++)                          \
    _Pragma("unroll") for (int ks = 0; ks < 2; ks++)                          \
        b[ni][ks] = *(const bf16x8*)&L[d][1][wh][((wn & 1) * 64               \
                        + (nfb + ni) * 16 + lr) * 64                          \
                        + (((lg + 4 * ks) ^ (lr & 7)) << 3)];
#define MFMAQ(mfb, nfb)                                                       \
    _Pragma("unroll") for (int mi = 0; mi < 4; mi++)                          \
    _Pragma("unroll") for (int ni = 0; ni < 2; ni++)                          \
    _Pragma("unroll") for (int ks = 0; ks < 2; ks++)                          \
        acc[mfb + mi][nfb + ni] = __builtin_amdgcn_mfma_f32_16x16x32_bf16(    \
            a[mi][ks], b[ni][ks], acc[mfb + mi][nfb + ni], 0, 0, 0);
#define PH_SYNC1()                                                            \
    __builtin_amdgcn_s_barrier();                                             \
    asm volatile("s_waitcnt lgkmcnt(0)" ::: "memory");                        \
    __builtin_amdgcn_sched_barrier(0);                                        \
    __builtin_amdgcn_s_setprio(1);
#define PH_SYNC2()                                                            \
    __builtin_amdgcn_s_setprio(0);                                            \
    __builtin_amdgcn_s_barrier();
#define PH_SYNC2V()                                                           \
    __builtin_amdgcn_s_setprio(0);                                            \
    asm volatile("s_waitcnt vmcnt(2)" ::: "memory");                          \
    __builtin_amdgcn_s_barrier();

template <int MODE>
__global__ __launch_bounds__(512, 2) void gemm256(
    const u16* __restrict__ A, const u16* __restrict__ Bt,
    u16* __restrict__ Cb, float* __restrict__ Cf,
    const float* __restrict__ resid, const float* __restrict__ bias,
    int M, int N, int K, int lda, int ldb, int mb)
{
    __shared__ u16 L[2][2][2][128 * 64];   // 128 KiB
    int nwg = gridDim.x, id = blockIdx.x;
    int sw = (id & 7) * (nwg >> 3) + (id >> 3);   // XCD swizzle (nwg%8==0)
    int bx = sw % mb, by = sw / mb;
    const int m0 = bx * 256, n0 = by * 256;

    const int tid = threadIdx.x;
    const int w = tid >> 6, l = tid & 63;
    const int wm = w >> 2, wn = w & 3, wh = wn >> 1;
    const int lg = l >> 4, lr = l & 15;

    const int srow = w * 16 + (l >> 3);          // staged row (+8 for 2nd load)
    const int sch8 = ((l & 7) ^ (l >> 3)) * 8;   // pre-swizzled source chunk

    // stage half h of K-tile t into dbuf d (2 x glds16 per thread)
    auto stA = [&](int d, int h, int t) {
        const u16* src = A + (size_t)(m0 + h * 128 + srow) * lda + t * 64 + sch8;
        u16* dst = &L[d][0][h][w * 1024];
        glds16(src, dst);
        glds16(src + (size_t)8 * lda, dst + 512);
    };
    auto stB = [&](int d, int h, int t) {
        const u16* src = Bt + (size_t)(n0 + h * 128 + srow) * ldb + t * 64 + sch8;
        u16* dst = &L[d][1][h][w * 1024];
        glds16(src, dst);
        glds16(src + (size_t)8 * ldb, dst + 512);
    };

    f32x4 acc[8][4];
#pragma unroll
    for (int i = 0; i < 8; i++)
#pragma unroll
        for (int j = 0; j < 4; j++) acc[i][j] = f32x4{0.f, 0.f, 0.f, 0.f};
    bf16x8 a[4][2], b[2][2];

    const int NI = K >> 7;   // iterations of 2 K-tiles

    // prologue: tile0 (buf0) + B0(tile1); allow tile1-B0 in flight
    stA(0, 0, 0); stA(0, 1, 0); stB(0, 0, 0); stB(0, 1, 0);
    stB(1, 0, 1);
    asm volatile("s_waitcnt vmcnt(2)" ::: "memory");
    __builtin_amdgcn_s_barrier();

#pragma unroll 1
    for (int j = 0; j < NI; j++) {
        const int t = 2 * j;
        const bool more = (j + 1 < NI);
        // ph1
        LDA4(0, 0); LDB2(0, 0);
        stA(1, 0, t + 1);
        PH_SYNC1(); MFMAQ(0, 0); PH_SYNC2();
        // ph2
        LDA4(0, 4);
        stA(1, 1, t + 1);
        PH_SYNC1(); MFMAQ(4, 0); PH_SYNC2();
        // ph3
        LDB2(0, 2);
        stB(1, 1, t + 1);
        PH_SYNC1(); MFMAQ(4, 2); PH_SYNC2();
        // ph4
        LDA4(0, 0);
        if (more) stB(0, 1, t + 2);
        PH_SYNC1(); MFMAQ(0, 2); PH_SYNC2V();
        // ph5
        LDA4(1, 0); LDB2(1, 0);
        if (more) stA(0, 0, t + 2);
        PH_SYNC1(); MFMAQ(0, 0); PH_SYNC2();
        // ph6
        LDA4(1, 4);
        if (more) stA(0, 1, t + 2);
        PH_SYNC1(); MFMAQ(4, 0); PH_SYNC2();
        // ph7
        LDB2(1, 2);
        if (more) stB(0, 0, t + 2);
        PH_SYNC1(); MFMAQ(4, 2); PH_SYNC2();
        // ph8
        LDA4(1, 0);
        if (more) stB(1, 0, t + 3);
        PH_SYNC1(); MFMAQ(0, 2); PH_SYNC2V();
    }

    // epilogue
#pragma unroll
    for (int mf = 0; mf < 8; mf++) {
#pragma unroll
        for (int nf = 0; nf < 4; nf++) {
#pragma unroll
            for (int e = 0; e < 4; e++) {
                int row = m0 + wm * 128 + mf * 16 + lg * 4 + e;
                int col = n0 + wn * 64 + nf * 16 + lr;
                float v = acc[mf][nf][e];
                size_t idx = (size_t)row * N + col;
                if constexpr (MODE == 0) {
                    Cb[idx] = f2bf(v);
                } else {
                    Cf[idx] = resid[idx] + v + bias[col];
                }
            }
        }
    }
}

// ------- bf16 MFMA GEMM, Bt input ([N][ldb]), 128x128 tile, 2-phase dbuf ------
// MODE 3: C = resid + A*B + bias -> f32 Cf (ffn2)
// MODE 4: split-K partial C = A*B -> f32 Cf[kz] (ffn1)
template <int MODE>
__global__ __launch_bounds__(256, 2) void gemm_bt(
    const u16* __restrict__ A, const u16* __restrict__ Bt,
    u16* __restrict__ Cb, float* __restrict__ Cf,
    const float* __restrict__ resid, const float* __restrict__ bias,
    int M, int N, int K, int lda, int ldb, int mb)
{
    __shared__ u16 As[2][128 * 32];
    __shared__ u16 Bs[2][128 * 32];
    int bx, by;
    if constexpr (MODE == 4) {
        bx = blockIdx.x; by = blockIdx.y;
        int kz = blockIdx.z;
        A += kz * 256;
        Bt += kz * 256;
        Cf += (size_t)kz * M * N;
    } else {
        int nwg = gridDim.x, id = blockIdx.x;
        int sw = (id & 7) * (nwg >> 3) + (id >> 3);
        bx = sw % mb; by = sw / mb;
    }
    const int tid = threadIdx.x;
    const int w = tid >> 6, l = tid & 63;
    const int wr = w >> 1, wc = w & 1;
    const int lg = l >> 4, lr = l & 15;
    const int m0 = bx * 128, n0 = by * 128;

    f32x4 zero = {0.f, 0.f, 0.f, 0.f};
    f32x4 acc[4][4];
#pragma unroll
    for (int i = 0; i < 4; i++)
#pragma unroll
        for (int j = 0; j < 4; j++) acc[i][j] = zero;

    const u16* Ag = A + (size_t)(m0 + w * 16 + (l >> 2)) * lda + (l & 3) * 8;
    const u16* Bg = Bt + (size_t)(n0 + w * 16 + (l >> 2)) * ldb + (l & 3) * 8;

    auto stage = [&](int b, int k0) {
        glds16(Ag + k0, &As[b][w * 512]);
        glds16(Ag + k0 + (size_t)64 * lda, &As[b][w * 512 + 2048]);
        glds16(Bg + k0, &Bs[b][w * 512]);
        glds16(Bg + k0 + (size_t)64 * ldb, &Bs[b][w * 512 + 2048]);
    };
    auto compute = [&](int b) {
        bf16x8 af[4], bfr[4];
#pragma unroll
        for (int t = 0; t < 4; t++)
            af[t] = *(const bf16x8*)&As[b][(wr * 64 + t * 16 + lr) * 32 + lg * 8];
#pragma unroll
        for (int t = 0; t < 4; t++)
            bfr[t] = *(const bf16x8*)&Bs[b][(wc * 64 + t * 16 + lr) * 32 + lg * 8];
#pragma unroll
        for (int i = 0; i < 4; i++)
#pragma unroll
            for (int j = 0; j < 4; j++)
                acc[i][j] = __builtin_amdgcn_mfma_f32_16x16x32_bf16(
                    af[i], bfr[j], acc[i][j], 0, 0, 0);
    };

    stage(0, 0);
    __syncthreads();
    int cur = 0;
    for (int k0 = 32; k0 < K; k0 += 32) {
        stage(cur ^ 1, k0);
        compute(cur);
        __syncthreads();
        cur ^= 1;
    }
    compute(cur);

#pragma unroll
    for (int i = 0; i < 4; i++) {
#pragma unroll
        for (int j = 0; j < 4; j++) {
#pragma unroll
            for (int e = 0; e < 4; e++) {
                int row = m0 + wr * 64 + i * 16 + lg * 4 + e;
                int col = n0 + wc * 64 + j * 16 + lr;
                float v = acc[i][j][e];
                size_t idx = (size_t)row * N + col;
                if constexpr (MODE == 3) {
                    Cf[idx] = resid[idx] + v + bias[col];
                } else {  // MODE 4: raw partial
                    Cf[idx] = v;
                }
            }
        }
    }
}

// ---------------- ffn1 split-K reduce: relu(sum4 + bias) -> bf16 --------------
__global__ __launch_bounds__(256) void relu_reduce4(
    const float* __restrict__ fp, const float* __restrict__ b1,
    u16* __restrict__ tb)
{
    const size_t CH = (size_t)MROWS * FFNP;
    size_t base = ((size_t)blockIdx.x * 256 + threadIdx.x) * 4;
    float4 s0 = *(const float4*)&fp[base];
    float4 s1 = *(const float4*)&fp[base + CH];
    float4 s2 = *(const float4*)&fp[base + 2 * CH];
    float4 s3 = *(const float4*)&fp[base + 3 * CH];
    int col = (int)(base & (FFNP - 1));
    float sv[4] = {s0.x + s1.x + s2.x + s3.x, s0.y + s1.y + s2.y + s3.y,
                   s0.z + s1.z + s2.z + s3.z, s0.w + s1.w + s2.w + s3.w};
    u16 o[4];
#pragma unroll
    for (int j = 0; j < 4; j++) {
        int c = col + j;
        float b = (c < 100) ? b1[c] : 0.f;
        o[j] = f2bf(fmaxf(sv[j] + b, 0.f));
    }
    uint2 pk;
    pk.x = (u32)o[0] | ((u32)o[1] << 16);
    pk.y = (u32)o[2] | ((u32)o[3] << 16);
    *(uint2*)&tb[base] = pk;
}

// ------ causal flash attention: 8 waves, QBLK=128, KVB=64, dbuf, pair-balanced
__global__ __launch_bounds__(512, 4) void attn_fwd(
    const u16* __restrict__ qkv, const u16* __restrict__ Vt,
    u16* __restrict__ Og)
{
    int xcd = blockIdx.x & 7;
    int j = blockIdx.x >> 3;
    int bh = xcd * 8 + (j & 7);
    int qp = j >> 3;                 // q-pair index 0..7
    int bb = bh >> 4, hh = bh & 15;

    int tid = threadIdx.x;
    int w = tid >> 6, l = tid & 63;
    int lg = l >> 4, lr = l & 15;

    const u16* Qb = qkv + ((size_t)bb * TDIM) * QSTR + hh * HS;
    const u16* Kb = Qb + 1024;
    const u16* Vb = Vt + (size_t)bh * HS * TDIM;

    __shared__ u16 Ks[2][64 * 64];   // [kv][d] XOR-swizzled 16B chunks
    __shared__ u16 Vs[2][64 * 64];   // [d][kv] XOR-swizzled
    __shared__ u16 Ps[8][16 * 64];   // per-wave P[q][kv], XOR-swizzled

    int srow8 = w * 8 + (l >> 3);
    int schunk = (l & 7) ^ ((l >> 3) & 7);
    u16* Pw = Ps[w];
    int sbase = (l & 48) + lg * 4;

    const float QSCL = 0.045084227f;          // 2^-5 * log2(e)

#pragma unroll 1
    for (int qi = 0; qi < 2; qi++) {
        int qb = (qi == 0 ? qp : 15 - qp) * 128;
        int q_abs = qb + w * 16 + lr;
        int wlo = qb + w * 16;
        int wmax = wlo + 15;
        int nt = qb / 64 + 2;

        bf16x8 qf[2];
        qf[0] = *(const bf16x8*)&Qb[(size_t)q_abs * QSTR + lg * 8];
        qf[1] = *(const bf16x8*)&Qb[(size_t)q_abs * QSTR + 32 + lg * 8];
#pragma unroll
        for (int i = 0; i < 8; i++) {
            qf[0][i] = (__bf16)((float)qf[0][i] * QSCL);
            qf[1][i] = (__bf16)((float)qf[1][i] * QSCL);
        }

        f32x4 zero = {0.f, 0.f, 0.f, 0.f};
        f32x4 oacc[4];
#pragma unroll
        for (int dt = 0; dt < 4; dt++) oacc[dt] = zero;
        float mstate = -1e30f, lstate = 0.f;

        auto stage = [&](int b, int kv0) {
            glds16(Kb + (size_t)(kv0 + srow8) * QSTR + schunk * 8, &Ks[b][w * 512]);
            glds16(Vb + (size_t)srow8 * TDIM + kv0 + schunk * 8, &Vs[b][w * 512]);
        };

        stage(0, 0);
        __syncthreads();
        int cur = 0;
#pragma unroll 1
        for (int t = 0; t < nt; t++) {
            int kv0 = t * 64;
            if (t + 1 < nt) stage(cur ^ 1, kv0 + 64);
            if (kv0 <= wmax) {
                const u16* Kc = Ks[cur];
                const u16* Vc = Vs[cur];
                f32x4 sc[4];
#pragma unroll
                for (int ct = 0; ct < 4; ct++) sc[ct] = zero;
                __builtin_amdgcn_s_setprio(1);
#pragma unroll
                for (int ct = 0; ct < 4; ct++) {
#pragma unroll
                    for (int dc = 0; dc < 2; dc++) {
                        bf16x8 kf = *(const bf16x8*)&Kc[(ct * 16 + lr) * 64 +
                                                        (((lg + 4 * dc) ^ (lr & 7)) << 3)];
                        sc[ct] = __builtin_amdgcn_mfma_f32_16x16x32_bf16(
                            kf, qf[dc], sc[ct], 0, 0, 0);
                    }
                }
                __builtin_amdgcn_s_setprio(0);
                float p[16];
                float mloc = -1e30f;
                if (kv0 + 63 > wlo) {
#pragma unroll
                    for (int ct = 0; ct < 4; ct++) {
#pragma unroll
                        for (int e = 0; e < 4; e++) {
                            float v = sc[ct][e];
                            if (kv0 + ct * 16 + lg * 4 + e > q_abs) v = -1e30f;
                            p[ct * 4 + e] = v;
                            mloc = fmaxf(mloc, v);
                        }
                    }
                } else {
#pragma unroll
                    for (int ct = 0; ct < 4; ct++) {
#pragma unroll
                        for (int e = 0; e < 4; e++) {
                            float v = sc[ct][e];
                            p[ct * 4 + e] = v;
                            mloc = fmaxf(mloc, v);
                        }
                    }
                }
                mloc = fmaxf(mloc, __shfl_xor(mloc, 16, 64));
                mloc = fmaxf(mloc, __shfl_xor(mloc, 32, 64));
                if (!__all(mloc - mstate <= 8.0f)) {
                    float mnew = fmaxf(mstate, mloc);
                    float scal = __builtin_amdgcn_exp2f(mstate - mnew);
                    mstate = mnew;
                    lstate *= scal;
                    float scalT[4];
#pragma unroll
                    for (int e = 0; e < 4; e++) scalT[e] = __shfl(scal, sbase + e, 64);
#pragma unroll
                    for (int dt = 0; dt < 4; dt++)
#pragma unroll
                        for (int e = 0; e < 4; e++) oacc[dt][e] *= scalT[e];
                }
                float psum = 0.f;
#pragma unroll
                for (int i = 0; i < 16; i++) {
                    p[i] = __builtin_amdgcn_exp2f(p[i] - mstate);
                    psum += p[i];
                }
                psum += __shfl_xor(psum, 16, 64);
                psum += __shfl_xor(psum, 32, 64);
                lstate += psum;
#pragma unroll
                for (int ct = 0; ct < 4; ct++) {
#pragma unroll
                    for (int i = 0; i < 2; i++) {
                        u32 word = (u32)f2bf(p[ct * 4 + 2 * i]) |
                                   ((u32)f2bf(p[ct * 4 + 2 * i + 1]) << 16);
                        int kvb = ct * 16 + lg * 4 + 2 * i;
                        int idx = lr * 64 + ((((kvb >> 3) ^ (lr & 7)) << 3) | (kvb & 7));
                        *(u32*)&Pw[idx] = word;
                    }
                }
                asm volatile("s_waitcnt lgkmcnt(0)" ::: "memory");
                __builtin_amdgcn_sched_barrier(0);
                __builtin_amdgcn_s_setprio(1);
#pragma unroll
                for (int m = 0; m < 2; m++) {
                    bf16x8 pa = *(const bf16x8*)&Pw[lr * 64 + (((lg + 4 * m) ^ (lr & 7)) << 3)];
#pragma unroll
                    for (int dt = 0; dt < 4; dt++) {
                        bf16x8 vf = *(const bf16x8*)&Vc[(dt * 16 + lr) * 64 +
                                                        (((lg + 4 * m) ^ (lr & 7)) << 3)];
                        oacc[dt] = __builtin_amdgcn_mfma_f32_16x16x32_bf16(
                            pa, vf, oacc[dt], 0, 0, 0);
                    }
                }
                __builtin_amdgcn_s_setprio(0);
            }
            __syncthreads();
            cur ^= 1;
        }
        float lT[4];
#pragma unroll
        for (int e = 0; e < 4; e++) lT[e] = __shfl(lstate, sbase + e, 64);
#pragma unroll
        for (int dt = 0; dt < 4; dt++) {
#pragma unroll
            for (int e = 0; e < 4; e++) {
                int row = qb + w * 16 + lg * 4 + e;
                Og[((size_t)bb * TDIM + row) * EDIM + hh * HS + dt * 16 + lr] =
                    f2bf(oacc[dt][e] / lT[e]);
            }
        }
    }
}

// -----------------------------------------------------------------------------
extern "C" void kernel_launch(void* const* d_in, const int* in_sizes, int n_in,
                              void* d_out, int out_size, void* d_ws, size_t ws_size,
                              hipStream_t stream)
{
    const float* x     = (const float*)d_in[0];
    const float* wq    = (const float*)d_in[1];
    const float* wk    = (const float*)d_in[2];
    const float* wv    = (const float*)d_in[3];
    const float* wproj = (const float*)d_in[4];
    const float* bproj = (const float*)d_in[5];
    const float* w1    = (const float*)d_in[6];
    const float* b1    = (const float*)d_in[7];
    const float* w2    = (const float*)d_in[8];
    const float* b2    = (const float*)d_in[9];
    const float* ln1g  = (const float*)d_in[10];
    const float* ln1b  = (const float*)d_in[11];
    const float* ln2g  = (const float*)d_in[12];
    const float* ln2b  = (const float*)d_in[13];
    float* out = (float*)d_out;

    char* ws = (char*)d_ws;
    size_t off = 0;
    auto alloc = [&](size_t bytes) -> void* {
        void* p = (void*)(ws + off);
        off += (bytes + 255) & ~(size_t)255;
        return p;
    };
    u16* hbuf = (u16*)alloc((size_t)MROWS * EDIM * 2);
    u16* qkv  = (u16*)alloc((size_t)MROWS * QSTR * 2);   // fused q|k|v
    u16* attb = (u16*)alloc((size_t)MROWS * EDIM * 2);
    u16* vt   = (u16*)alloc((size_t)MROWS * EDIM * 2);
    u16* wqkvt = (u16*)alloc((size_t)QSTR * EDIM * 2);
    u16* wpt  = (u16*)alloc((size_t)EDIM * EDIM * 2);
    u16* w1t  = (u16*)alloc((size_t)FFNP * EDIM * 2);
    u16* w2t  = (u16*)alloc((size_t)EDIM * FFNP * 2);
    // FFN-phase aliases (attention-phase buffers dead by then)
    float* fp = (float*)qkv;  // 4 x MROWS x FFNP f32 = 16.8 MB <= qkv (50 MB)
    u16* tb   = vt;

    transpose_pad<<<dim3(16, 16), 256, 0, stream>>>(wq, wqkvt, EDIM, EDIM, EDIM, EDIM);
    transpose_pad<<<dim3(16, 16), 256, 0, stream>>>(wk, wqkvt + (size_t)EDIM * EDIM,
                                                    EDIM, EDIM, EDIM, EDIM);
    transpose_pad<<<dim3(16, 16), 256, 0, stream>>>(wv, wqkvt + (size_t)2 * EDIM * EDIM,
                                                    EDIM, EDIM, EDIM, EDIM);
    transpose_pad<<<dim3(16, 16), 256, 0, stream>>>(wproj, wpt, EDIM, EDIM, EDIM, EDIM);
    transpose_pad<<<dim3(16, 2), 256, 0, stream>>>(w1, w1t, EDIM, 100, EDIM, FFNP);
    transpose_pad<<<dim3(2, 16), 256, 0, stream>>>(w2, w2t, 100, EDIM, FFNP, EDIM);

    ln_rows<<<MROWS / 4, 256, 0, stream>>>(x, ln1g, ln1b, hbuf);
    // fused QKV: [8192,1024] x [3072,1024]^T, 256^2 8-phase, 384 blocks
    gemm256<0><<<dim3(384), 512, 0, stream>>>(hbuf, wqkvt, qkv, nullptr, nullptr,
                                              nullptr, MROWS, QSTR, EDIM, EDIM, EDIM, 32);
    vtrans<<<dim3(TDIM / 64, HDIM, BDIM), 256, 0, stream>>>(qkv, vt);
    attn_fwd<<<dim3(512), 512, 0, stream>>>(qkv, vt, attb);
    // proj + residual, 256^2 8-phase, 128 blocks
    gemm256<1><<<dim3(128), 512, 0, stream>>>(attb, wpt, nullptr, out, x, bproj,
                                              MROWS, EDIM, EDIM, EDIM, EDIM, 32);
    ln_rows<<<MROWS / 4, 256, 0, stream>>>(out, ln2g, ln2b, hbuf);
    gemm_bt<4><<<dim3(64, 1, 4), 256, 0, stream>>>(hbuf, w1t, nullptr, fp, nullptr,
                                                   nullptr, MROWS, FFNP, 256, EDIM, EDIM, 64);
    relu_reduce4<<<dim3(MROWS * FFNP / 1024), 256, 0, stream>>>(fp, b1, tb);
    gemm_bt<3><<<dim3(512), 256, 0, stream>>>(tb, w2t, nullptr, out, out, b2,
                                              MROWS, EDIM, FFNP, FFNP, FFNP, 64);
}

// Round 7
// 252.987 us; speedup vs baseline: 1.0800x; 1.0800x over previous
//
#include <hip/hip_runtime.h>

typedef unsigned short u16;
typedef unsigned int u32;
typedef __bf16 bf16x8 __attribute__((ext_vector_type(8)));
typedef float f32x4 __attribute__((ext_vector_type(4)));

#define BDIM 4
#define TDIM 2048
#define EDIM 1024
#define HDIM 16
#define HS 64
#define MROWS (BDIM * TDIM)
#define FFNP 128   // FFN_HID=100 padded to 128
#define QSTR 3072  // fused qkv row stride

__device__ __forceinline__ u16 f2bf(float f) {
    __bf16 h = (__bf16)f;
    return __builtin_bit_cast(u16, h);
}

__device__ __forceinline__ void glds16(const void* g, void* l) {
    __builtin_amdgcn_global_load_lds(
        (__attribute__((address_space(1))) const void*)g,
        (__attribute__((address_space(3))) void*)l, 16, 0, 0);
}

// ------------- 4x fused weight transpose (1024x1024, no padding) --------------
__global__ __launch_bounds__(256) void transpose4(
    const float* __restrict__ s0, const float* __restrict__ s1,
    const float* __restrict__ s2, const float* __restrict__ s3,
    u16* __restrict__ d0, u16* __restrict__ d1,
    u16* __restrict__ d2, u16* __restrict__ d3)
{
    __shared__ u16 sm[64][72];
    const float* src; u16* dst;
    switch (blockIdx.z) {
        case 0: src = s0; dst = d0; break;
        case 1: src = s1; dst = d1; break;
        case 2: src = s2; dst = d2; break;
        default: src = s3; dst = d3; break;
    }
    int k0 = blockIdx.x * 64, n0 = blockIdx.y * 64;
    int tid = threadIdx.x;
#pragma unroll
    for (int i = 0; i < 16; i++) {
        int idx = i * 256 + tid;
        int kl = idx >> 6, nl = idx & 63;
        sm[kl][nl] = f2bf(src[(size_t)(k0 + kl) * EDIM + n0 + nl]);
    }
    __syncthreads();
#pragma unroll
    for (int i = 0; i < 16; i++) {
        int idx = i * 256 + tid;
        int nl = idx >> 6, kl = idx & 63;
        dst[(size_t)(n0 + nl) * EDIM + k0 + kl] = sm[kl][nl];
    }
}

// ---------------- weight transpose + f32->bf16 (+zero padding) ----------------
__global__ __launch_bounds__(256) void transpose_pad(
    const float* __restrict__ src, u16* __restrict__ dst,
    int K, int N, int Kpad, int Npad)
{
    __shared__ u16 sm[64][72];
    int k0 = blockIdx.x * 64, n0 = blockIdx.y * 64;
    int tid = threadIdx.x;
#pragma unroll
    for (int i = 0; i < 16; i++) {
        int idx = i * 256 + tid;
        int kl = idx >> 6, nl = idx & 63;
        int k = k0 + kl, n = n0 + nl;
        float v = (k < K && n < N) ? src[(size_t)k * N + n] : 0.f;
        sm[kl][nl] = f2bf(v);
    }
    __syncthreads();
#pragma unroll
    for (int i = 0; i < 16; i++) {
        int idx = i * 256 + tid;
        int nl = idx >> 6, kl = idx & 63;
        int n = n0 + nl, k = k0 + kl;
        if (n < Npad && k < Kpad) dst[(size_t)n * Kpad + k] = sm[kl][nl];
    }
}

// ---------------- V transpose per head: qkv[B,T,3072] -> [(B*H)*HS][T] --------
__global__ __launch_bounds__(256) void vtrans(
    const u16* __restrict__ qkv, u16* __restrict__ vt)
{
    __shared__ u16 sm[64][65];
    int t0 = blockIdx.x * 64, h = blockIdx.y, b = blockIdx.z;
    int tid = threadIdx.x;
    int r = tid >> 3, c8 = (tid & 7) * 8;
#pragma unroll
    for (int rr = 0; rr < 2; rr++) {
        int row = r + rr * 32;
        union { uint4 v; u16 us[8]; } u;
        u.v = *(const uint4*)&qkv[((size_t)b * TDIM + t0 + row) * QSTR + 2048 + h * HS + c8];
#pragma unroll
        for (int e = 0; e < 8; e++) sm[row][c8 + e] = u.us[e];
    }
    __syncthreads();
#pragma unroll
    for (int rr = 0; rr < 2; rr++) {
        int d = r + rr * 32;
        union { uint4 v; u16 us[8]; } u;
#pragma unroll
        for (int e = 0; e < 8; e++) u.us[e] = sm[c8 + e][d];
        *(uint4*)&vt[((size_t)(b * HDIM + h) * HS + d) * TDIM + t0 + c8] = u.v;
    }
}

// ---------------- LayerNorm rows (one wave per row), f32 in -> bf16 out -------
__global__ __launch_bounds__(256) void ln_rows(
    const float* __restrict__ X, const float* __restrict__ G,
    const float* __restrict__ Bv, u16* __restrict__ H)
{
    int w = threadIdx.x >> 6, l = threadIdx.x & 63;
    int row = blockIdx.x * 4 + w;
    const float* xr = X + (size_t)row * EDIM;
    float4 v[4];
    float s = 0.f, s2 = 0.f;
#pragma unroll
    for (int i = 0; i < 4; i++) {
        v[i] = *(const float4*)&xr[l * 4 + i * 256];
        s += v[i].x + v[i].y + v[i].z + v[i].w;
        s2 += v[i].x * v[i].x + v[i].y * v[i].y + v[i].z * v[i].z + v[i].w * v[i].w;
    }
#pragma unroll
    for (int off = 1; off < 64; off <<= 1) {
        s += __shfl_xor(s, off, 64);
        s2 += __shfl_xor(s2, off, 64);
    }
    float mean = s * (1.f / EDIM);
    float var = s2 * (1.f / EDIM) - mean * mean;
    float rstd = rsqrtf(var + 1e-5f);
#pragma unroll
    for (int i = 0; i < 4; i++) {
        int c = l * 4 + i * 256;
        float4 gg = *(const float4*)&G[c];
        float4 bb = *(const float4*)&Bv[c];
        u16 o0 = f2bf((v[i].x - mean) * rstd * gg.x + bb.x);
        u16 o1 = f2bf((v[i].y - mean) * rstd * gg.y + bb.y);
        u16 o2 = f2bf((v[i].z - mean) * rstd * gg.z + bb.z);
        u16 o3 = f2bf((v[i].w - mean) * rstd * gg.w + bb.w);
        uint2 pk;
        pk.x = (u32)o0 | ((u32)o1 << 16);
        pk.y = (u32)o2 | ((u32)o3 << 16);
        *(uint2*)&H[(size_t)row * EDIM + c] = pk;
    }
}

// ======= 256x256 8-phase GEMM (T2+T3+T4+T5), Bt input ([N][ldb]) ==============
// MODE 0: C = A*B -> bf16 Cb.  MODE 1: C = resid + A*B + bias -> f32 Cf.
// Stage map (iter j, t=2j): ph1:A0(t+1) ph2:A1(t+1) ph3:B1(t+1) ph4:B1(t+2)
// ph5:A0(t+2) ph6:A1(t+2) ph7:B0(t+2) ph8:B0(t+3); B0(t+1) staged prev ph8.
// RAW: counted vmcnt at ph4/ph8 (2 in steady state; 0 in the final iteration
// where only 8 loads are in flight -- r6 latent race fixed).
#define LDA4(d, mfb)                                                          \
    _Pragma("unroll") for (int mi = 0; mi < 4; mi++)                          \
    _Pragma("unroll") for (int ks = 0; ks < 2; ks++)                          \
        a[mi][ks] = *(const bf16x8*)&L[d][0][wm][((mfb + mi) * 16 + lr) * 64  \
                        + (((lg + 4 * ks) ^ (lr & 7)) << 3)];
#define LDB2(d, nfb)                                                          \
    _Pragma("unroll") for (int ni = 0; ni < 2; ni++)                          \
    _Pragma("unroll") for (int ks = 0; ks < 2; ks++)                          \
        b[ni][ks] = *(const bf16x8*)&L[d][1][wh][((wn & 1) * 64               \
                        + (nfb + ni) * 16 + lr) * 64                          \
                        + (((lg + 4 * ks) ^ (lr & 7)) << 3)];
#define MFMAQ(mfb, nfb)                                                       \
    _Pragma("unroll") for (int mi = 0; mi < 4; mi++)                          \
    _Pragma("unroll") for (int ni = 0; ni < 2; ni++)                          \
    _Pragma("unroll") for (int ks = 0; ks < 2; ks++)                          \
        acc[mfb + mi][nfb + ni] = __builtin_amdgcn_mfma_f32_16x16x32_bf16(    \
            a[mi][ks], b[ni][ks], acc[mfb + mi][nfb + ni], 0, 0, 0);
#define PH_SYNC1()                                                            \
    __builtin_amdgcn_s_barrier();                                             \
    asm volatile("s_waitcnt lgkmcnt(0)" ::: "memory");                        \
    __builtin_amdgcn_sched_barrier(0);                                        \
    __builtin_amdgcn_s_setprio(1);
#define PH_SYNC2()                                                            \
    __builtin_amdgcn_s_setprio(0);                                            \
    __builtin_amdgcn_s_barrier();
#define PH_SYNC2V(cond)                                                       \
    __builtin_amdgcn_s_setprio(0);                                            \
    if (cond) { asm volatile("s_waitcnt vmcnt(2)" ::: "memory"); }            \
    else      { asm volatile("s_waitcnt vmcnt(0)" ::: "memory"); }            \
    __builtin_amdgcn_s_barrier();

template <int MODE>
__global__ __launch_bounds__(512, 2) void gemm256(
    const u16* __restrict__ A, const u16* __restrict__ Bt,
    u16* __restrict__ Cb, float* __restrict__ Cf,
    const float* __restrict__ resid, const float* __restrict__ bias,
    int M, int N, int K, int lda, int ldb, int mb)
{
    __shared__ u16 L[2][2][2][128 * 64];   // 128 KiB
    int nwg = gridDim.x, id = blockIdx.x;
    int sw = (id & 7) * (nwg >> 3) + (id >> 3);   // XCD swizzle (nwg%8==0)
    int bx = sw % mb, by = sw / mb;
    const int m0 = bx * 256, n0 = by * 256;

    const int tid = threadIdx.x;
    const int w = tid >> 6, l = tid & 63;
    const int wm = w >> 2, wn = w & 3, wh = wn >> 1;
    const int lg = l >> 4, lr = l & 15;

    const int srow = w * 16 + (l >> 3);
    const int sch8 = ((l & 7) ^ (l >> 3)) * 8;   // pre-swizzled source chunk

    auto stA = [&](int d, int h, int t) {
        const u16* src = A + (size_t)(m0 + h * 128 + srow) * lda + t * 64 + sch8;
        u16* dst = &L[d][0][h][w * 1024];
        glds16(src, dst);
        glds16(src + (size_t)8 * lda, dst + 512);
    };
    auto stB = [&](int d, int h, int t) {
        const u16* src = Bt + (size_t)(n0 + h * 128 + srow) * ldb + t * 64 + sch8;
        u16* dst = &L[d][1][h][w * 1024];
        glds16(src, dst);
        glds16(src + (size_t)8 * ldb, dst + 512);
    };

    f32x4 acc[8][4];
#pragma unroll
    for (int i = 0; i < 8; i++)
#pragma unroll
        for (int j = 0; j < 4; j++) acc[i][j] = f32x4{0.f, 0.f, 0.f, 0.f};
    bf16x8 a[4][2], b[2][2];

    const int NI = K >> 7;   // iterations of 2 K-tiles

    stA(0, 0, 0); stA(0, 1, 0); stB(0, 0, 0); stB(0, 1, 0);
    stB(1, 0, 1);
    asm volatile("s_waitcnt vmcnt(2)" ::: "memory");
    __builtin_amdgcn_s_barrier();

#pragma unroll 1
    for (int j = 0; j < NI; j++) {
        const int t = 2 * j;
        const bool more = (j + 1 < NI);
        // ph1
        LDA4(0, 0); LDB2(0, 0);
        stA(1, 0, t + 1);
        PH_SYNC1(); MFMAQ(0, 0); PH_SYNC2();
        // ph2
        LDA4(0, 4);
        stA(1, 1, t + 1);
        PH_SYNC1(); MFMAQ(4, 0); PH_SYNC2();
        // ph3
        LDB2(0, 2);
        stB(1, 1, t + 1);
        PH_SYNC1(); MFMAQ(4, 2); PH_SYNC2();
        // ph4
        LDA4(0, 0);
        if (more) stB(0, 1, t + 2);
        PH_SYNC1(); MFMAQ(0, 2); PH_SYNC2V(more);
        // ph5
        LDA4(1, 0); LDB2(1, 0);
        if (more) stA(0, 0, t + 2);
        PH_SYNC1(); MFMAQ(0, 0); PH_SYNC2();
        // ph6
        LDA4(1, 4);
        if (more) stA(0, 1, t + 2);
        PH_SYNC1(); MFMAQ(4, 0); PH_SYNC2();
        // ph7
        LDB2(1, 2);
        if (more) stB(0, 0, t + 2);
        PH_SYNC1(); MFMAQ(4, 2); PH_SYNC2();
        // ph8
        LDA4(1, 0);
        if (more) stB(1, 0, t + 3);
        PH_SYNC1(); MFMAQ(0, 2); PH_SYNC2V(more);
    }

#pragma unroll
    for (int mf = 0; mf < 8; mf++) {
#pragma unroll
        for (int nf = 0; nf < 4; nf++) {
#pragma unroll
            for (int e = 0; e < 4; e++) {
                int row = m0 + wm * 128 + mf * 16 + lg * 4 + e;
                int col = n0 + wn * 64 + nf * 16 + lr;
                float v = acc[mf][nf][e];
                size_t idx = (size_t)row * N + col;
                if constexpr (MODE == 0) {
                    Cb[idx] = f2bf(v);
                } else {
                    Cf[idx] = resid[idx] + v + bias[col];
                }
            }
        }
    }
}

// ------- bf16 MFMA GEMM, Bt input ([N][ldb]), 128x128 tile, 2-phase dbuf ------
// MODE 3: C = resid + A*B + bias -> f32 Cf (ffn2)
// MODE 4: split-K partial C = A*B -> f32 Cf[kz] (ffn1)
template <int MODE>
__global__ __launch_bounds__(256, 2) void gemm_bt(
    const u16* __restrict__ A, const u16* __restrict__ Bt,
    u16* __restrict__ Cb, float* __restrict__ Cf,
    const float* __restrict__ resid, const float* __restrict__ bias,
    int M, int N, int K, int lda, int ldb, int mb)
{
    __shared__ u16 As[2][128 * 32];
    __shared__ u16 Bs[2][128 * 32];
    int bx, by;
    if constexpr (MODE == 4) {
        bx = blockIdx.x; by = blockIdx.y;
        int kz = blockIdx.z;
        A += kz * 256;
        Bt += kz * 256;
        Cf += (size_t)kz * M * N;
    } else {
        int nwg = gridDim.x, id = blockIdx.x;
        int sw = (id & 7) * (nwg >> 3) + (id >> 3);
        bx = sw % mb; by = sw / mb;
    }
    const int tid = threadIdx.x;
    const int w = tid >> 6, l = tid & 63;
    const int wr = w >> 1, wc = w & 1;
    const int lg = l >> 4, lr = l & 15;
    const int m0 = bx * 128, n0 = by * 128;

    f32x4 zero = {0.f, 0.f, 0.f, 0.f};
    f32x4 acc[4][4];
#pragma unroll
    for (int i = 0; i < 4; i++)
#pragma unroll
        for (int j = 0; j < 4; j++) acc[i][j] = zero;

    const u16* Ag = A + (size_t)(m0 + w * 16 + (l >> 2)) * lda + (l & 3) * 8;
    const u16* Bg = Bt + (size_t)(n0 + w * 16 + (l >> 2)) * ldb + (l & 3) * 8;

    auto stage = [&](int b, int k0) {
        glds16(Ag + k0, &As[b][w * 512]);
        glds16(Ag + k0 + (size_t)64 * lda, &As[b][w * 512 + 2048]);
        glds16(Bg + k0, &Bs[b][w * 512]);
        glds16(Bg + k0 + (size_t)64 * ldb, &Bs[b][w * 512 + 2048]);
    };
    auto compute = [&](int b) {
        bf16x8 af[4], bfr[4];
#pragma unroll
        for (int t = 0; t < 4; t++)
            af[t] = *(const bf16x8*)&As[b][(wr * 64 + t * 16 + lr) * 32 + lg * 8];
#pragma unroll
        for (int t = 0; t < 4; t++)
            bfr[t] = *(const bf16x8*)&Bs[b][(wc * 64 + t * 16 + lr) * 32 + lg * 8];
#pragma unroll
        for (int i = 0; i < 4; i++)
#pragma unroll
            for (int j = 0; j < 4; j++)
                acc[i][j] = __builtin_amdgcn_mfma_f32_16x16x32_bf16(
                    af[i], bfr[j], acc[i][j], 0, 0, 0);
    };

    stage(0, 0);
    __syncthreads();
    int cur = 0;
    for (int k0 = 32; k0 < K; k0 += 32) {
        stage(cur ^ 1, k0);
        compute(cur);
        __syncthreads();
        cur ^= 1;
    }
    compute(cur);

#pragma unroll
    for (int i = 0; i < 4; i++) {
#pragma unroll
        for (int j = 0; j < 4; j++) {
#pragma unroll
            for (int e = 0; e < 4; e++) {
                int row = m0 + wr * 64 + i * 16 + lg * 4 + e;
                int col = n0 + wc * 64 + j * 16 + lr;
                float v = acc[i][j][e];
                size_t idx = (size_t)row * N + col;
                if constexpr (MODE == 3) {
                    Cf[idx] = resid[idx] + v + bias[col];
                } else {  // MODE 4: raw partial
                    Cf[idx] = v;
                }
            }
        }
    }
}

// ---------------- ffn1 split-K reduce: relu(sum4 + bias) -> bf16 --------------
__global__ __launch_bounds__(256) void relu_reduce4(
    const float* __restrict__ fp, const float* __restrict__ b1,
    u16* __restrict__ tb)
{
    const size_t CH = (size_t)MROWS * FFNP;
    size_t base = ((size_t)blockIdx.x * 256 + threadIdx.x) * 4;
    float4 s0 = *(const float4*)&fp[base];
    float4 s1 = *(const float4*)&fp[base + CH];
    float4 s2 = *(const float4*)&fp[base + 2 * CH];
    float4 s3 = *(const float4*)&fp[base + 3 * CH];
    int col = (int)(base & (FFNP - 1));
    float sv[4] = {s0.x + s1.x + s2.x + s3.x, s0.y + s1.y + s2.y + s3.y,
                   s0.z + s1.z + s2.z + s3.z, s0.w + s1.w + s2.w + s3.w};
    u16 o[4];
#pragma unroll
    for (int j = 0; j < 4; j++) {
        int c = col + j;
        float b = (c < 100) ? b1[c] : 0.f;
        o[j] = f2bf(fmaxf(sv[j] + b, 0.f));
    }
    uint2 pk;
    pk.x = (u32)o[0] | ((u32)o[1] << 16);
    pk.y = (u32)o[2] | ((u32)o[3] << 16);
    *(uint2*)&tb[base] = pk;
}

// --- causal flash attention: 4 waves, QBLK=64, KVB=64, dbuf, pair-balanced ----
// 1024 blocks x 40KB LDS = exactly 4 blocks/CU: 4 independent barrier groups
// per CU so one block's serial softmax overlaps another's MFMA/staging.
__global__ __launch_bounds__(256, 4) void attn_fwd(
    const u16* __restrict__ qkv, const u16* __restrict__ Vt,
    u16* __restrict__ Og)
{
    // XCD-grouped: xcd owns 8 consecutive bh; all 16 q-pair blocks of a head
    // land on the same XCD (K/V L2 reuse). 1024 blocks, bijective.
    int xcd = blockIdx.x & 7;
    int j = blockIdx.x >> 3;          // 0..127
    int bh = xcd * 8 + (j & 7);
    int qp = j >> 3;                  // q-pair index 0..15
    int bb = bh >> 4, hh = bh & 15;

    int tid = threadIdx.x;
    int w = tid >> 6, l = tid & 63;
    int lg = l >> 4, lr = l & 15;

    const u16* Qb = qkv + ((size_t)bb * TDIM) * QSTR + hh * HS;
    const u16* Kb = Qb + 1024;
    const u16* Vb = Vt + (size_t)bh * HS * TDIM;

    __shared__ u16 Ks[2][64 * 64];   // [kv][d] XOR-swizzled 16B chunks
    __shared__ u16 Vs[2][64 * 64];   // [d][kv] XOR-swizzled
    __shared__ u16 Ps[4][16 * 64];   // per-wave P[q][kv], XOR-swizzled

    int srow = w * 16 + (l >> 3);             // staged row (16 rows/wave)
    int schunk = (l & 7) ^ ((l >> 3) & 7);    // pre-swizzled source chunk
    u16* Pw = Ps[w];
    int sbase = (l & 48) + lg * 4;

    const float QSCL = 0.045084227f;          // 2^-5 * log2(e)

#pragma unroll 1
    for (int qi = 0; qi < 2; qi++) {
        int qb = (qi == 0 ? qp : 31 - qp) * 64;
        int q_abs = qb + w * 16 + lr;
        int wlo = qb + w * 16;
        int nt = qb / 64 + 1;                  // kv tiles for this q-block

        bf16x8 qf[2];
        qf[0] = *(const bf16x8*)&Qb[(size_t)q_abs * QSTR + lg * 8];
        qf[1] = *(const bf16x8*)&Qb[(size_t)q_abs * QSTR + 32 + lg * 8];
#pragma unroll
        for (int i = 0; i < 8; i++) {
            qf[0][i] = (__bf16)((float)qf[0][i] * QSCL);
            qf[1][i] = (__bf16)((float)qf[1][i] * QSCL);
        }

        f32x4 zero = {0.f, 0.f, 0.f, 0.f};
        f32x4 oacc[4];
#pragma unroll
        for (int dt = 0; dt < 4; dt++) oacc[dt] = zero;
        float mstate = -1e30f, lstate = 0.f;   // log2 domain, q = lr per lane

        auto stage = [&](int b, int kv0) {
            glds16(Kb + (size_t)(kv0 + srow) * QSTR + schunk * 8, &Ks[b][w * 1024]);
            glds16(Kb + (size_t)(kv0 + srow + 8) * QSTR + schunk * 8,
                   &Ks[b][w * 1024 + 512]);
            glds16(Vb + (size_t)srow * TDIM + kv0 + schunk * 8, &Vs[b][w * 1024]);
            glds16(Vb + (size_t)(srow + 8) * TDIM + kv0 + schunk * 8,
                   &Vs[b][w * 1024 + 512]);
        };

        stage(0, 0);
        __syncthreads();
        int cur = 0;
#pragma unroll 1
        for (int t = 0; t < nt; t++) {
            int kv0 = t * 64;
            if (t + 1 < nt) stage(cur ^ 1, kv0 + 64);
            const u16* Kc = Ks[cur];
            const u16* Vc = Vs[cur];
            // S^T = K * Q^T  (lane: q = lr, kv = ct*16 + lg*4 + e)
            f32x4 sc[4];
#pragma unroll
            for (int ct = 0; ct < 4; ct++) sc[ct] = zero;
            __builtin_amdgcn_s_setprio(1);
#pragma unroll
            for (int ct = 0; ct < 4; ct++) {
#pragma unroll
                for (int dc = 0; dc < 2; dc++) {
                    bf16x8 kf = *(const bf16x8*)&Kc[(ct * 16 + lr) * 64 +
                                                    (((lg + 4 * dc) ^ (lr & 7)) << 3)];
                    sc[ct] = __builtin_amdgcn_mfma_f32_16x16x32_bf16(
                        kf, qf[dc], sc[ct], 0, 0, 0);
                }
            }
            __builtin_amdgcn_s_setprio(0);
            // softmax, log2 domain; mask only on diagonal tiles (kv0+63 > wlo)
            float p[16];
            float mloc = -1e30f;
            if (kv0 + 63 > wlo) {
#pragma unroll
                for (int ct = 0; ct < 4; ct++) {
#pragma unroll
                    for (int e = 0; e < 4; e++) {
                        float v = sc[ct][e];
                        if (kv0 + ct * 16 + lg * 4 + e > q_abs) v = -1e30f;
                        p[ct * 4 + e] = v;
                        mloc = fmaxf(mloc, v);
                    }
                }
            } else {
#pragma unroll
                for (int ct = 0; ct < 4; ct++) {
#pragma unroll
                    for (int e = 0; e < 4; e++) {
                        float v = sc[ct][e];
                        p[ct * 4 + e] = v;
                        mloc = fmaxf(mloc, v);
                    }
                }
            }
            mloc = fmaxf(mloc, __shfl_xor(mloc, 16, 64));
            mloc = fmaxf(mloc, __shfl_xor(mloc, 32, 64));
            // defer-max: only rescale when max grew by > 8 (P bounded by 2^8)
            if (!__all(mloc - mstate <= 8.0f)) {
                float mnew = fmaxf(mstate, mloc);
                float scal = __builtin_amdgcn_exp2f(mstate - mnew);
                mstate = mnew;
                lstate *= scal;
                float scalT[4];
#pragma unroll
                for (int e = 0; e < 4; e++) scalT[e] = __shfl(scal, sbase + e, 64);
#pragma unroll
                for (int dt = 0; dt < 4; dt++)
#pragma unroll
                    for (int e = 0; e < 4; e++) oacc[dt][e] *= scalT[e];
            }
            float psum = 0.f;
#pragma unroll
            for (int i = 0; i < 16; i++) {
                p[i] = __builtin_amdgcn_exp2f(p[i] - mstate);
                psum += p[i];
            }
            psum += __shfl_xor(psum, 16, 64);
            psum += __shfl_xor(psum, 32, 64);
            lstate += psum;
            // write P[q=lr][kv] packed u32, XOR-swizzled
#pragma unroll
            for (int ct = 0; ct < 4; ct++) {
#pragma unroll
                for (int i = 0; i < 2; i++) {
                    u32 word = (u32)f2bf(p[ct * 4 + 2 * i]) |
                               ((u32)f2bf(p[ct * 4 + 2 * i + 1]) << 16);
                    int kvb = ct * 16 + lg * 4 + 2 * i;
                    int idx = lr * 64 + ((((kvb >> 3) ^ (lr & 7)) << 3) | (kvb & 7));
                    *(u32*)&Pw[idx] = word;
                }
            }
            asm volatile("s_waitcnt lgkmcnt(0)" ::: "memory");
            __builtin_amdgcn_sched_barrier(0);
            __builtin_amdgcn_s_setprio(1);
#pragma unroll
            for (int m = 0; m < 2; m++) {
                bf16x8 pa = *(const bf16x8*)&Pw[lr * 64 + (((lg + 4 * m) ^ (lr & 7)) << 3)];
#pragma unroll
                for (int dt = 0; dt < 4; dt++) {
                    bf16x8 vf = *(const bf16x8*)&Vc[(dt * 16 + lr) * 64 +
                                                    (((lg + 4 * m) ^ (lr & 7)) << 3)];
                    oacc[dt] = __builtin_amdgcn_mfma_f32_16x16x32_bf16(
                        pa, vf, oacc[dt], 0, 0, 0);
                }
            }
            __builtin_amdgcn_s_setprio(0);
            __syncthreads();
            cur ^= 1;
        }
        float lT[4];
#pragma unroll
        for (int e = 0; e < 4; e++) lT[e] = __shfl(lstate, sbase + e, 64);
#pragma unroll
        for (int dt = 0; dt < 4; dt++) {
#pragma unroll
            for (int e = 0; e < 4; e++) {
                int row = qb + w * 16 + lg * 4 + e;
                Og[((size_t)bb * TDIM + row) * EDIM + hh * HS + dt * 16 + lr] =
                    f2bf(oacc[dt][e] / lT[e]);
            }
        }
    }
}

// -----------------------------------------------------------------------------
extern "C" void kernel_launch(void* const* d_in, const int* in_sizes, int n_in,
                              void* d_out, int out_size, void* d_ws, size_t ws_size,
                              hipStream_t stream)
{
    const float* x     = (const float*)d_in[0];
    const float* wq    = (const float*)d_in[1];
    const float* wk    = (const float*)d_in[2];
    const float* wv    = (const float*)d_in[3];
    const float* wproj = (const float*)d_in[4];
    const float* bproj = (const float*)d_in[5];
    const float* w1    = (const float*)d_in[6];
    const float* b1    = (const float*)d_in[7];
    const float* w2    = (const float*)d_in[8];
    const float* b2    = (const float*)d_in[9];
    const float* ln1g  = (const float*)d_in[10];
    const float* ln1b  = (const float*)d_in[11];
    const float* ln2g  = (const float*)d_in[12];
    const float* ln2b  = (const float*)d_in[13];
    float* out = (float*)d_out;

    char* ws = (char*)d_ws;
    size_t off = 0;
    auto alloc = [&](size_t bytes) -> void* {
        void* p = (void*)(ws + off);
        off += (bytes + 255) & ~(size_t)255;
        return p;
    };
    u16* hbuf = (u16*)alloc((size_t)MROWS * EDIM * 2);
    u16* qkv  = (u16*)alloc((size_t)MROWS * QSTR * 2);   // fused q|k|v
    u16* attb = (u16*)alloc((size_t)MROWS * EDIM * 2);
    u16* vt   = (u16*)alloc((size_t)MROWS * EDIM * 2);
    u16* wqkvt = (u16*)alloc((size_t)QSTR * EDIM * 2);
    u16* wpt  = (u16*)alloc((size_t)EDIM * EDIM * 2);
    u16* w1t  = (u16*)alloc((size_t)FFNP * EDIM * 2);
    u16* w2t  = (u16*)alloc((size_t)EDIM * FFNP * 2);
    // FFN-phase aliases (attention-phase buffers dead by then)
    float* fp = (float*)qkv;  // 4 x MROWS x FFNP f32 = 16.8 MB <= qkv (50 MB)
    u16* tb   = vt;

    transpose4<<<dim3(16, 16, 4), 256, 0, stream>>>(
        wq, wk, wv, wproj,
        wqkvt, wqkvt + (size_t)EDIM * EDIM, wqkvt + (size_t)2 * EDIM * EDIM, wpt);
    transpose_pad<<<dim3(16, 2), 256, 0, stream>>>(w1, w1t, EDIM, 100, EDIM, FFNP);
    transpose_pad<<<dim3(2, 16), 256, 0, stream>>>(w2, w2t, 100, EDIM, FFNP, EDIM);

    ln_rows<<<MROWS / 4, 256, 0, stream>>>(x, ln1g, ln1b, hbuf);
    // fused QKV: [8192,1024] x [3072,1024]^T, 256^2 8-phase, 384 blocks
    gemm256<0><<<dim3(384), 512, 0, stream>>>(hbuf, wqkvt, qkv, nullptr, nullptr,
                                              nullptr, MROWS, QSTR, EDIM, EDIM, EDIM, 32);
    vtrans<<<dim3(TDIM / 64, HDIM, BDIM), 256, 0, stream>>>(qkv, vt);
    attn_fwd<<<dim3(1024), 256, 0, stream>>>(qkv, vt, attb);
    // proj + residual, 256^2 8-phase, 128 blocks
    gemm256<1><<<dim3(128), 512, 0, stream>>>(attb, wpt, nullptr, out, x, bproj,
                                              MROWS, EDIM, EDIM, EDIM, EDIM, 32);
    ln_rows<<<MROWS / 4, 256, 0, stream>>>(out, ln2g, ln2b, hbuf);
    gemm_bt<4><<<dim3(64, 1, 4), 256, 0, stream>>>(hbuf, w1t, nullptr, fp, nullptr,
                                                   nullptr, MROWS, FFNP, 256, EDIM, EDIM, 64);
    relu_reduce4<<<dim3(MROWS * FFNP / 1024), 256, 0, stream>>>(fp, b1, tb);
    gemm_bt<3><<<dim3(512), 256, 0, stream>>>(tb, w2t, nullptr, out, out, b2,
                                              MROWS, EDIM, FFNP, FFNP, FFNP, 64);
}

// Round 8
// 236.521 us; speedup vs baseline: 1.1552x; 1.0696x over previous
//
#include <hip/hip_runtime.h>

typedef unsigned short u16;
typedef unsigned int u32;
typedef __bf16 bf16x8 __attribute__((ext_vector_type(8)));
typedef float f32x4 __attribute__((ext_vector_type(4)));

#define BDIM 4
#define TDIM 2048
#define EDIM 1024
#define HDIM 16
#define HS 64
#define MROWS (BDIM * TDIM)
#define FFNP 128   // FFN_HID=100 padded to 128

__device__ __forceinline__ u16 f2bf(float f) {
    __bf16 h = (__bf16)f;
    return __builtin_bit_cast(u16, h);
}

__device__ __forceinline__ void glds16(const void* g, void* l) {
    __builtin_amdgcn_global_load_lds(
        (__attribute__((address_space(1))) const void*)g,
        (__attribute__((address_space(3))) void*)l, 16, 0, 0);
}

// ------------- 4x fused weight transpose (1024x1024, no padding) --------------
__global__ __launch_bounds__(256) void transpose4(
    const float* __restrict__ s0, const float* __restrict__ s1,
    const float* __restrict__ s2, const float* __restrict__ s3,
    u16* __restrict__ d0, u16* __restrict__ d1,
    u16* __restrict__ d2, u16* __restrict__ d3)
{
    __shared__ u16 sm[64][72];
    const float* src; u16* dst;
    switch (blockIdx.z) {
        case 0: src = s0; dst = d0; break;
        case 1: src = s1; dst = d1; break;
        case 2: src = s2; dst = d2; break;
        default: src = s3; dst = d3; break;
    }
    int k0 = blockIdx.x * 64, n0 = blockIdx.y * 64;
    int tid = threadIdx.x;
#pragma unroll
    for (int i = 0; i < 16; i++) {
        int idx = i * 256 + tid;
        int kl = idx >> 6, nl = idx & 63;
        sm[kl][nl] = f2bf(src[(size_t)(k0 + kl) * EDIM + n0 + nl]);
    }
    __syncthreads();
#pragma unroll
    for (int i = 0; i < 16; i++) {
        int idx = i * 256 + tid;
        int nl = idx >> 6, kl = idx & 63;
        dst[(size_t)(n0 + nl) * EDIM + k0 + kl] = sm[kl][nl];
    }
}

// ---------------- weight transpose + f32->bf16 (+zero padding) ----------------
__global__ __launch_bounds__(256) void transpose_pad(
    const float* __restrict__ src, u16* __restrict__ dst,
    int K, int N, int Kpad, int Npad)
{
    __shared__ u16 sm[64][72];
    int k0 = blockIdx.x * 64, n0 = blockIdx.y * 64;
    int tid = threadIdx.x;
#pragma unroll
    for (int i = 0; i < 16; i++) {
        int idx = i * 256 + tid;
        int kl = idx >> 6, nl = idx & 63;
        int k = k0 + kl, n = n0 + nl;
        float v = (k < K && n < N) ? src[(size_t)k * N + n] : 0.f;
        sm[kl][nl] = f2bf(v);
    }
    __syncthreads();
#pragma unroll
    for (int i = 0; i < 16; i++) {
        int idx = i * 256 + tid;
        int nl = idx >> 6, kl = idx & 63;
        int n = n0 + nl, k = k0 + kl;
        if (n < Npad && k < Kpad) dst[(size_t)n * Kpad + k] = sm[kl][nl];
    }
}

// ---------------- LayerNorm rows (one wave per row), f32 in -> bf16 out -------
__global__ __launch_bounds__(256) void ln_rows(
    const float* __restrict__ X, const float* __restrict__ G,
    const float* __restrict__ Bv, u16* __restrict__ H)
{
    int w = threadIdx.x >> 6, l = threadIdx.x & 63;
    int row = blockIdx.x * 4 + w;
    const float* xr = X + (size_t)row * EDIM;
    float4 v[4];
    float s = 0.f, s2 = 0.f;
#pragma unroll
    for (int i = 0; i < 4; i++) {
        v[i] = *(const float4*)&xr[l * 4 + i * 256];
        s += v[i].x + v[i].y + v[i].z + v[i].w;
        s2 += v[i].x * v[i].x + v[i].y * v[i].y + v[i].z * v[i].z + v[i].w * v[i].w;
    }
#pragma unroll
    for (int off = 1; off < 64; off <<= 1) {
        s += __shfl_xor(s, off, 64);
        s2 += __shfl_xor(s2, off, 64);
    }
    float mean = s * (1.f / EDIM);
    float var = s2 * (1.f / EDIM) - mean * mean;
    float rstd = rsqrtf(var + 1e-5f);
#pragma unroll
    for (int i = 0; i < 4; i++) {
        int c = l * 4 + i * 256;
        float4 gg = *(const float4*)&G[c];
        float4 bb = *(const float4*)&Bv[c];
        u16 o0 = f2bf((v[i].x - mean) * rstd * gg.x + bb.x);
        u16 o1 = f2bf((v[i].y - mean) * rstd * gg.y + bb.y);
        u16 o2 = f2bf((v[i].z - mean) * rstd * gg.z + bb.z);
        u16 o3 = f2bf((v[i].w - mean) * rstd * gg.w + bb.w);
        uint2 pk;
        pk.x = (u32)o0 | ((u32)o1 << 16);
        pk.y = (u32)o2 | ((u32)o3 << 16);
        *(uint2*)&H[(size_t)row * EDIM + c] = pk;
    }
}

// ======= 256x256 8-phase GEMM (T2+T3+T4+T5), Bt input ([N][ldb]) ==============
// MODE 1: C = resid + A*B + bias -> f32 Cf  (proj)
// MODE 5: combined QKV: blocks 0-255 compute qk = hbuf x [wq|wk]^T (bf16, row
//         stride 2048); blocks 256-383 compute V^T = wvt x hbuf^T and write
//         it per-head transposed to vt via index remap (replaces vtrans).
#define LDA4(d, mfb)                                                          \
    _Pragma("unroll") for (int mi = 0; mi < 4; mi++)                          \
    _Pragma("unroll") for (int ks = 0; ks < 2; ks++)                          \
        a[mi][ks] = *(const bf16x8*)&L[d][0][wm][((mfb + mi) * 16 + lr) * 64  \
                        + (((lg + 4 * ks) ^ (lr & 7)) << 3)];
#define LDB2(d, nfb)                                                          \
    _Pragma("unroll") for (int ni = 0; ni < 2; ni++)                          \
    _Pragma("unroll") for (int ks = 0; ks < 2; ks++)                          \
        b[ni][ks] = *(const bf16x8*)&L[d][1][wh][((wn & 1) * 64               \
                        + (nfb + ni) * 16 + lr) * 64                          \
                        + (((lg + 4 * ks) ^ (lr & 7)) << 3)];
#define MFMAQ(mfb, nfb)                                                       \
    _Pragma("unroll") for (int mi = 0; mi < 4; mi++)                          \
    _Pragma("unroll") for (int ni = 0; ni < 2; ni++)                          \
    _Pragma("unroll") for (int ks = 0; ks < 2; ks++)                          \
        acc[mfb + mi][nfb + ni] = __builtin_amdgcn_mfma_f32_16x16x32_bf16(    \
            a[mi][ks], b[ni][ks], acc[mfb + mi][nfb + ni], 0, 0, 0);
#define PH_SYNC1()                                                            \
    __builtin_amdgcn_s_barrier();                                             \
    asm volatile("s_waitcnt lgkmcnt(0)" ::: "memory");                        \
    __builtin_amdgcn_sched_barrier(0);                                        \
    __builtin_amdgcn_s_setprio(1);
#define PH_SYNC2()                                                            \
    __builtin_amdgcn_s_setprio(0);                                            \
    __builtin_amdgcn_s_barrier();
#define PH_SYNC2V(cond)                                                       \
    __builtin_amdgcn_s_setprio(0);                                            \
    if (cond) { asm volatile("s_waitcnt vmcnt(2)" ::: "memory"); }            \
    else      { asm volatile("s_waitcnt vmcnt(0)" ::: "memory"); }            \
    __builtin_amdgcn_s_barrier();

template <int MODE>
__global__ __launch_bounds__(512, 2) void gemm256(
    const u16* __restrict__ A, const u16* __restrict__ Bt,
    u16* __restrict__ Cb, float* __restrict__ Cf,
    const float* __restrict__ resid, const float* __restrict__ bias,
    int M, int N, int K, int lda, int ldb, int mb)
{
    __shared__ u16 L[2][2][2][128 * 64];   // 128 KiB
    const u16 *pA, *pB;
    int LA, LB, NN, bx, by;
    bool vmode = false;
    if constexpr (MODE == 5) {
        int id = blockIdx.x;
        if (id < 256) {            // QK part: 32 x 8 tiles
            int sw = (id & 7) * 32 + (id >> 3);
            bx = sw % 32; by = sw / 32;
            pA = A; pB = Bt; LA = 1024; LB = 1024; NN = 2048;
        } else {                   // V part: 4 x 32 tiles (M=1024, N=8192)
            id -= 256;
            int sw = (id & 7) * 16 + (id >> 3);
            bx = sw % 4; by = sw / 4;
            pA = Bt + (size_t)2048 * 1024;   // wvt
            pB = A;                          // hbuf
            LA = 1024; LB = 1024; NN = 8192;
            vmode = true;
        }
    } else {
        int nwg = gridDim.x, id = blockIdx.x;
        int sw = (id & 7) * (nwg >> 3) + (id >> 3);   // XCD swizzle (nwg%8==0)
        bx = sw % mb; by = sw / mb;
        pA = A; pB = Bt; LA = lda; LB = ldb; NN = N;
    }
    const int m0 = bx * 256, n0 = by * 256;

    const int tid = threadIdx.x;
    const int w = tid >> 6, l = tid & 63;
    const int wm = w >> 2, wn = w & 3, wh = wn >> 1;
    const int lg = l >> 4, lr = l & 15;

    const int srow = w * 16 + (l >> 3);
    const int sch8 = ((l & 7) ^ (l >> 3)) * 8;   // pre-swizzled source chunk

    auto stA = [&](int d, int h, int t) {
        const u16* src = pA + (size_t)(m0 + h * 128 + srow) * LA + t * 64 + sch8;
        u16* dst = &L[d][0][h][w * 1024];
        glds16(src, dst);
        glds16(src + (size_t)8 * LA, dst + 512);
    };
    auto stB = [&](int d, int h, int t) {
        const u16* src = pB + (size_t)(n0 + h * 128 + srow) * LB + t * 64 + sch8;
        u16* dst = &L[d][1][h][w * 1024];
        glds16(src, dst);
        glds16(src + (size_t)8 * LB, dst + 512);
    };

    f32x4 acc[8][4];
#pragma unroll
    for (int i = 0; i < 8; i++)
#pragma unroll
        for (int j = 0; j < 4; j++) acc[i][j] = f32x4{0.f, 0.f, 0.f, 0.f};
    bf16x8 a[4][2], b[2][2];

    const int NI = K >> 7;   // iterations of 2 K-tiles

    stA(0, 0, 0); stA(0, 1, 0); stB(0, 0, 0); stB(0, 1, 0);
    stB(1, 0, 1);
    asm volatile("s_waitcnt vmcnt(2)" ::: "memory");
    __builtin_amdgcn_s_barrier();

#pragma unroll 1
    for (int j = 0; j < NI; j++) {
        const int t = 2 * j;
        const bool more = (j + 1 < NI);
        // ph1
        LDA4(0, 0); LDB2(0, 0);
        stA(1, 0, t + 1);
        PH_SYNC1(); MFMAQ(0, 0); PH_SYNC2();
        // ph2
        LDA4(0, 4);
        stA(1, 1, t + 1);
        PH_SYNC1(); MFMAQ(4, 0); PH_SYNC2();
        // ph3
        LDB2(0, 2);
        stB(1, 1, t + 1);
        PH_SYNC1(); MFMAQ(4, 2); PH_SYNC2();
        // ph4
        LDA4(0, 0);
        if (more) stB(0, 1, t + 2);
        PH_SYNC1(); MFMAQ(0, 2); PH_SYNC2V(more);
        // ph5
        LDA4(1, 0); LDB2(1, 0);
        if (more) stA(0, 0, t + 2);
        PH_SYNC1(); MFMAQ(0, 0); PH_SYNC2();
        // ph6
        LDA4(1, 4);
        if (more) stA(0, 1, t + 2);
        PH_SYNC1(); MFMAQ(4, 0); PH_SYNC2();
        // ph7
        LDB2(1, 2);
        if (more) stB(0, 0, t + 2);
        PH_SYNC1(); MFMAQ(4, 2); PH_SYNC2();
        // ph8
        LDA4(1, 0);
        if (more) stB(1, 0, t + 3);
        PH_SYNC1(); MFMAQ(0, 2); PH_SYNC2V(more);
    }

#pragma unroll
    for (int mf = 0; mf < 8; mf++) {
#pragma unroll
        for (int nf = 0; nf < 4; nf++) {
#pragma unroll
            for (int e = 0; e < 4; e++) {
                int row = m0 + wm * 128 + mf * 16 + lg * 4 + e;
                int col = n0 + wn * 64 + nf * 16 + lr;
                float v = acc[mf][nf][e];
                if constexpr (MODE == 5) {
                    if (!vmode) {
                        Cb[(size_t)row * 2048 + col] = f2bf(v);
                    } else {
                        // row = h*64+d (0..1023), col = b*2048 + t
                        u16* vtp = (u16*)Cf;
                        int bq = col >> 11, tt = col & 2047;
                        vtp[((size_t)bq * 1024 + row) * 2048 + tt] = f2bf(v);
                    }
                } else {
                    size_t idx = (size_t)row * NN + col;
                    Cf[idx] = resid[idx] + v + bias[col];
                }
            }
        }
    }
}

// ------- bf16 MFMA GEMM, Bt input ([N][ldb]), 128x128 tile, 2-phase dbuf ------
// MODE 3: C = resid + A*B + bias -> f32 Cf (ffn2)
// MODE 4: split-K partial C = A*B -> f32 Cf[kz] (ffn1)
template <int MODE>
__global__ __launch_bounds__(256, 2) void gemm_bt(
    const u16* __restrict__ A, const u16* __restrict__ Bt,
    u16* __restrict__ Cb, float* __restrict__ Cf,
    const float* __restrict__ resid, const float* __restrict__ bias,
    int M, int N, int K, int lda, int ldb, int mb)
{
    __shared__ u16 As[2][128 * 32];
    __shared__ u16 Bs[2][128 * 32];
    int bx, by;
    if constexpr (MODE == 4) {
        bx = blockIdx.x; by = blockIdx.y;
        int kz = blockIdx.z;
        A += kz * 256;
        Bt += kz * 256;
        Cf += (size_t)kz * M * N;
    } else {
        int nwg = gridDim.x, id = blockIdx.x;
        int sw = (id & 7) * (nwg >> 3) + (id >> 3);
        bx = sw % mb; by = sw / mb;
    }
    const int tid = threadIdx.x;
    const int w = tid >> 6, l = tid & 63;
    const int wr = w >> 1, wc = w & 1;
    const int lg = l >> 4, lr = l & 15;
    const int m0 = bx * 128, n0 = by * 128;

    f32x4 zero = {0.f, 0.f, 0.f, 0.f};
    f32x4 acc[4][4];
#pragma unroll
    for (int i = 0; i < 4; i++)
#pragma unroll
        for (int j = 0; j < 4; j++) acc[i][j] = zero;

    const u16* Ag = A + (size_t)(m0 + w * 16 + (l >> 2)) * lda + (l & 3) * 8;
    const u16* Bg = Bt + (size_t)(n0 + w * 16 + (l >> 2)) * ldb + (l & 3) * 8;

    auto stage = [&](int b, int k0) {
        glds16(Ag + k0, &As[b][w * 512]);
        glds16(Ag + k0 + (size_t)64 * lda, &As[b][w * 512 + 2048]);
        glds16(Bg + k0, &Bs[b][w * 512]);
        glds16(Bg + k0 + (size_t)64 * ldb, &Bs[b][w * 512 + 2048]);
    };
    auto compute = [&](int b) {
        bf16x8 af[4], bfr[4];
#pragma unroll
        for (int t = 0; t < 4; t++)
            af[t] = *(const bf16x8*)&As[b][(wr * 64 + t * 16 + lr) * 32 + lg * 8];
#pragma unroll
        for (int t = 0; t < 4; t++)
            bfr[t] = *(const bf16x8*)&Bs[b][(wc * 64 + t * 16 + lr) * 32 + lg * 8];
#pragma unroll
        for (int i = 0; i < 4; i++)
#pragma unroll
            for (int j = 0; j < 4; j++)
                acc[i][j] = __builtin_amdgcn_mfma_f32_16x16x32_bf16(
                    af[i], bfr[j], acc[i][j], 0, 0, 0);
    };

    stage(0, 0);
    __syncthreads();
    int cur = 0;
    for (int k0 = 32; k0 < K; k0 += 32) {
        stage(cur ^ 1, k0);
        compute(cur);
        __syncthreads();
        cur ^= 1;
    }
    compute(cur);

#pragma unroll
    for (int i = 0; i < 4; i++) {
#pragma unroll
        for (int j = 0; j < 4; j++) {
#pragma unroll
            for (int e = 0; e < 4; e++) {
                int row = m0 + wr * 64 + i * 16 + lg * 4 + e;
                int col = n0 + wc * 64 + j * 16 + lr;
                float v = acc[i][j][e];
                size_t idx = (size_t)row * N + col;
                if constexpr (MODE == 3) {
                    Cf[idx] = resid[idx] + v + bias[col];
                } else {  // MODE 4: raw partial
                    Cf[idx] = v;
                }
            }
        }
    }
}

// ---------------- ffn1 split-K reduce: relu(sum4 + bias) -> bf16 --------------
__global__ __launch_bounds__(256) void relu_reduce4(
    const float* __restrict__ fp, const float* __restrict__ b1,
    u16* __restrict__ tb)
{
    const size_t CH = (size_t)MROWS * FFNP;
    size_t base = ((size_t)blockIdx.x * 256 + threadIdx.x) * 4;
    float4 s0 = *(const float4*)&fp[base];
    float4 s1 = *(const float4*)&fp[base + CH];
    float4 s2 = *(const float4*)&fp[base + 2 * CH];
    float4 s3 = *(const float4*)&fp[base + 3 * CH];
    int col = (int)(base & (FFNP - 1));
    float sv[4] = {s0.x + s1.x + s2.x + s3.x, s0.y + s1.y + s2.y + s3.y,
                   s0.z + s1.z + s2.z + s3.z, s0.w + s1.w + s2.w + s3.w};
    u16 o[4];
#pragma unroll
    for (int j = 0; j < 4; j++) {
        int c = col + j;
        float b = (c < 100) ? b1[c] : 0.f;
        o[j] = f2bf(fmaxf(sv[j] + b, 0.f));
    }
    uint2 pk;
    pk.x = (u32)o[0] | ((u32)o[1] << 16);
    pk.y = (u32)o[2] | ((u32)o[3] << 16);
    *(uint2*)&tb[base] = pk;
}

// --- causal flash attention: 4 waves, QBLK=64, KVB=64, dbuf, pair-balanced ----
// No-max softmax: scores are q.k/32 * log2e with LN'd inputs (|s| < ~4), so
// softmax shift-invariance permits a fixed shift of 0 -- no max tracking,
// no rescale, no per-tile cross-lane ops (lane-partial l reduced once at end).
__global__ __launch_bounds__(256, 4) void attn_fwd(
    const u16* __restrict__ qk, const u16* __restrict__ Vt,
    u16* __restrict__ Og)
{
    int xcd = blockIdx.x & 7;
    int j = blockIdx.x >> 3;          // 0..127
    int bh = xcd * 8 + (j & 7);
    int qp = j >> 3;                  // q-pair index 0..15
    int bb = bh >> 4, hh = bh & 15;

    int tid = threadIdx.x;
    int w = tid >> 6, l = tid & 63;
    int lg = l >> 4, lr = l & 15;

    const u16* Qb = qk + ((size_t)bb * TDIM) * 2048 + hh * HS;
    const u16* Kb = Qb + 1024;
    const u16* Vb = Vt + (size_t)bh * HS * TDIM;

    __shared__ u16 Ks[2][64 * 64];   // [kv][d] XOR-swizzled 16B chunks
    __shared__ u16 Vs[2][64 * 64];   // [d][kv] XOR-swizzled
    __shared__ u16 Ps[4][16 * 64];   // per-wave P[q][kv], XOR-swizzled

    int srow = w * 16 + (l >> 3);             // staged row (16 rows/wave)
    int schunk = (l & 7) ^ ((l >> 3) & 7);    // pre-swizzled source chunk
    u16* Pw = Ps[w];
    int sbase = (l & 48) + lg * 4;

    const float QSCL = 0.045084227f;          // 2^-5 * log2(e)

#pragma unroll 1
    for (int qi = 0; qi < 2; qi++) {
        int qb = (qi == 0 ? qp : 31 - qp) * 64;
        int q_abs = qb + w * 16 + lr;
        int wlo = qb + w * 16;
        int nt = qb / 64 + 1;                  // kv tiles for this q-block

        bf16x8 qf[2];
        qf[0] = *(const bf16x8*)&Qb[(size_t)q_abs * 2048 + lg * 8];
        qf[1] = *(const bf16x8*)&Qb[(size_t)q_abs * 2048 + 32 + lg * 8];
#pragma unroll
        for (int i = 0; i < 8; i++) {
            qf[0][i] = (__bf16)((float)qf[0][i] * QSCL);
            qf[1][i] = (__bf16)((float)qf[1][i] * QSCL);
        }

        f32x4 zero = {0.f, 0.f, 0.f, 0.f};
        f32x4 oacc[4];
#pragma unroll
        for (int dt = 0; dt < 4; dt++) oacc[dt] = zero;
        float lpart = 0.f;                     // per-lane partial denominator

        auto stage = [&](int b, int kv0) {
            glds16(Kb + (size_t)(kv0 + srow) * 2048 + schunk * 8, &Ks[b][w * 1024]);
            glds16(Kb + (size_t)(kv0 + srow + 8) * 2048 + schunk * 8,
                   &Ks[b][w * 1024 + 512]);
            glds16(Vb + (size_t)srow * TDIM + kv0 + schunk * 8, &Vs[b][w * 1024]);
            glds16(Vb + (size_t)(srow + 8) * TDIM + kv0 + schunk * 8,
                   &Vs[b][w * 1024 + 512]);
        };

        stage(0, 0);
        __syncthreads();
        int cur = 0;
#pragma unroll 1
        for (int t = 0; t < nt; t++) {
            int kv0 = t * 64;
            if (t + 1 < nt) stage(cur ^ 1, kv0 + 64);
            const u16* Kc = Ks[cur];
            const u16* Vc = Vs[cur];
            // S^T = K * Q^T  (lane: q = lr, kv = ct*16 + lg*4 + e)
            f32x4 sc[4];
#pragma unroll
            for (int ct = 0; ct < 4; ct++) sc[ct] = zero;
            __builtin_amdgcn_s_setprio(1);
#pragma unroll
            for (int ct = 0; ct < 4; ct++) {
#pragma unroll
                for (int dc = 0; dc < 2; dc++) {
                    bf16x8 kf = *(const bf16x8*)&Kc[(ct * 16 + lr) * 64 +
                                                    (((lg + 4 * dc) ^ (lr & 7)) << 3)];
                    sc[ct] = __builtin_amdgcn_mfma_f32_16x16x32_bf16(
                        kf, qf[dc], sc[ct], 0, 0, 0);
                }
            }
            __builtin_amdgcn_s_setprio(0);
            // prefetch V fragments (independent of P; overlaps softmax VALU)
            bf16x8 vfr[2][4];
#pragma unroll
            for (int m = 0; m < 2; m++)
#pragma unroll
                for (int dt = 0; dt < 4; dt++)
                    vfr[m][dt] = *(const bf16x8*)&Vc[(dt * 16 + lr) * 64 +
                                                     (((lg + 4 * m) ^ (lr & 7)) << 3)];
            // softmax, log2 domain, fixed shift 0; mask only diag tiles
            float p[16];
            if (kv0 + 63 > wlo) {
#pragma unroll
                for (int ct = 0; ct < 4; ct++) {
#pragma unroll
                    for (int e = 0; e < 4; e++) {
                        float v = sc[ct][e];
                        if (kv0 + ct * 16 + lg * 4 + e > q_abs) v = -1e30f;
                        p[ct * 4 + e] = v;
                    }
                }
            } else {
#pragma unroll
                for (int ct = 0; ct < 4; ct++) {
#pragma unroll
                    for (int e = 0; e < 4; e++) p[ct * 4 + e] = sc[ct][e];
                }
            }
            float psum = 0.f;
#pragma unroll
            for (int i = 0; i < 16; i++) {
                p[i] = __builtin_amdgcn_exp2f(p[i]);   // exp2(-1e30) = 0
                psum += p[i];
            }
            lpart += psum;
            // write P[q=lr][kv] packed u32, XOR-swizzled
#pragma unroll
            for (int ct = 0; ct < 4; ct++) {
#pragma unroll
                for (int i = 0; i < 2; i++) {
                    u32 word = (u32)f2bf(p[ct * 4 + 2 * i]) |
                               ((u32)f2bf(p[ct * 4 + 2 * i + 1]) << 16);
                    int kvb = ct * 16 + lg * 4 + 2 * i;
                    int idx = lr * 64 + ((((kvb >> 3) ^ (lr & 7)) << 3) | (kvb & 7));
                    *(u32*)&Pw[idx] = word;
                }
            }
            asm volatile("s_waitcnt lgkmcnt(0)" ::: "memory");
            __builtin_amdgcn_sched_barrier(0);
            __builtin_amdgcn_s_setprio(1);
#pragma unroll
            for (int m = 0; m < 2; m++) {
                bf16x8 pa = *(const bf16x8*)&Pw[lr * 64 + (((lg + 4 * m) ^ (lr & 7)) << 3)];
#pragma unroll
                for (int dt = 0; dt < 4; dt++) {
                    oacc[dt] = __builtin_amdgcn_mfma_f32_16x16x32_bf16(
                        pa, vfr[m][dt], oacc[dt], 0, 0, 0);
                }
            }
            __builtin_amdgcn_s_setprio(0);
            __syncthreads();
            cur ^= 1;
        }
        // single end-of-block denominator reduce
        float lsum = lpart;
        lsum += __shfl_xor(lsum, 16, 64);
        lsum += __shfl_xor(lsum, 32, 64);
        float lT[4];
#pragma unroll
        for (int e = 0; e < 4; e++) lT[e] = __shfl(lsum, sbase + e, 64);
#pragma unroll
        for (int dt = 0; dt < 4; dt++) {
#pragma unroll
            for (int e = 0; e < 4; e++) {
                int row = qb + w * 16 + lg * 4 + e;
                Og[((size_t)bb * TDIM + row) * EDIM + hh * HS + dt * 16 + lr] =
                    f2bf(oacc[dt][e] / lT[e]);
            }
        }
    }
}

// -----------------------------------------------------------------------------
extern "C" void kernel_launch(void* const* d_in, const int* in_sizes, int n_in,
                              void* d_out, int out_size, void* d_ws, size_t ws_size,
                              hipStream_t stream)
{
    const float* x     = (const float*)d_in[0];
    const float* wq    = (const float*)d_in[1];
    const float* wk    = (const float*)d_in[2];
    const float* wv    = (const float*)d_in[3];
    const float* wproj = (const float*)d_in[4];
    const float* bproj = (const float*)d_in[5];
    const float* w1    = (const float*)d_in[6];
    const float* b1    = (const float*)d_in[7];
    const float* w2    = (const float*)d_in[8];
    const float* b2    = (const float*)d_in[9];
    const float* ln1g  = (const float*)d_in[10];
    const float* ln1b  = (const float*)d_in[11];
    const float* ln2g  = (const float*)d_in[12];
    const float* ln2b  = (const float*)d_in[13];
    float* out = (float*)d_out;

    char* ws = (char*)d_ws;
    size_t off = 0;
    auto alloc = [&](size_t bytes) -> void* {
        void* p = (void*)(ws + off);
        off += (bytes + 255) & ~(size_t)255;
        return p;
    };
    u16* hbuf = (u16*)alloc((size_t)MROWS * EDIM * 2);
    u16* qk   = (u16*)alloc((size_t)MROWS * 2048 * 2);   // fused q|k
    u16* attb = (u16*)alloc((size_t)MROWS * EDIM * 2);
    u16* vt   = (u16*)alloc((size_t)MROWS * EDIM * 2);
    u16* wqkvt = (u16*)alloc((size_t)3072 * EDIM * 2);   // q|k|v transposed
    u16* wpt  = (u16*)alloc((size_t)EDIM * EDIM * 2);
    u16* w1t  = (u16*)alloc((size_t)FFNP * EDIM * 2);
    u16* w2t  = (u16*)alloc((size_t)EDIM * FFNP * 2);
    // FFN-phase aliases (attention-phase buffers dead by then)
    float* fp = (float*)qk;   // 4 x MROWS x FFNP f32 = 16.8 MB <= qk (33.5 MB)
    u16* tb   = vt;

    transpose4<<<dim3(16, 16, 4), 256, 0, stream>>>(
        wq, wk, wv, wproj,
        wqkvt, wqkvt + (size_t)EDIM * EDIM, wqkvt + (size_t)2 * EDIM * EDIM, wpt);
    transpose_pad<<<dim3(16, 2), 256, 0, stream>>>(w1, w1t, EDIM, 100, EDIM, FFNP);
    transpose_pad<<<dim3(2, 16), 256, 0, stream>>>(w2, w2t, 100, EDIM, FFNP, EDIM);

    ln_rows<<<MROWS / 4, 256, 0, stream>>>(x, ln1g, ln1b, hbuf);
    // combined QK (256 tiles) + V-transposed (128 tiles) in one launch
    gemm256<5><<<dim3(384), 512, 0, stream>>>(hbuf, wqkvt, qk, (float*)vt,
                                              nullptr, nullptr,
                                              MROWS, 2048, EDIM, EDIM, EDIM, 32);
    attn_fwd<<<dim3(1024), 256, 0, stream>>>(qk, vt, attb);
    // proj + residual, 256^2 8-phase, 128 blocks
    gemm256<1><<<dim3(128), 512, 0, stream>>>(attb, wpt, nullptr, out, x, bproj,
                                              MROWS, EDIM, EDIM, EDIM, EDIM, 32);
    ln_rows<<<MROWS / 4, 256, 0, stream>>>(out, ln2g, ln2b, hbuf);
    gemm_bt<4><<<dim3(64, 1, 4), 256, 0, stream>>>(hbuf, w1t, nullptr, fp, nullptr,
                                                   nullptr, MROWS, FFNP, 256, EDIM, EDIM, 64);
    relu_reduce4<<<dim3(MROWS * FFNP / 1024), 256, 0, stream>>>(fp, b1, tb);
    gemm_bt<3><<<dim3(512), 256, 0, stream>>>(tb, w2t, nullptr, out, out, b2,
                                              MROWS, EDIM, FFNP, FFNP, FFNP, 64);
}